// Round 1
// baseline (306.375 us; speedup 1.0000x reference)
//
#include <hip/hip_runtime.h>
#include <cstdint>

typedef _Float16 half8 __attribute__((ext_vector_type(8)));
typedef unsigned short ushort8 __attribute__((ext_vector_type(8)));
typedef float floatx4 __attribute__((ext_vector_type(4)));

__device__ __forceinline__ unsigned short f2h(float f) {
    union { _Float16 h; unsigned short u; } cv;
    cv.h = (_Float16)f;
    return cv.u;
}

// ---------------- cast x fp32 -> fp16 ----------------
__global__ void cast_x_kernel(const float* __restrict__ x, unsigned short* __restrict__ xh, int n8) {
    int idx = blockIdx.x * blockDim.x + threadIdx.x;
    if (idx >= n8) return;
    const float4* p = (const float4*)x;
    float4 a = p[idx * 2], b = p[idx * 2 + 1];
    ushort8 o;
    o[0] = f2h(a.x); o[1] = f2h(a.y); o[2] = f2h(a.z); o[3] = f2h(a.w);
    o[4] = f2h(b.x); o[5] = f2h(b.y); o[6] = f2h(b.z); o[7] = f2h(b.w);
    *(ushort8*)(xh + (size_t)idx * 8) = o;
}

// ---------------- transpose + cast: in[R][C] fp32 -> out[C][R] fp16 ----------------
__global__ void transpose_cast_kernel(const float* __restrict__ in, unsigned short* __restrict__ out,
                                      int R, int C) {
    __shared__ float tile[32][33];
    int bx = blockIdx.x * 32;  // C block
    int by = blockIdx.y * 32;  // R block
    int x = threadIdx.x, y0 = threadIdx.y;
    #pragma unroll
    for (int k = 0; k < 4; k++) {
        int y = y0 + k * 8;
        tile[y][x] = in[(size_t)(by + y) * C + bx + x];
    }
    __syncthreads();
    #pragma unroll
    for (int k = 0; k < 4; k++) {
        int y = y0 + k * 8;
        out[(size_t)(bx + y) * R + by + x] = f2h(tile[x][y]);
    }
}

// ---------------- GEMM: C[M][N] = A[M][K] (fp16,row-major) * Bt[N][K] (fp16) ----------------
// mode 0: q epilogue (scale 0.125, store [b,h,i,d] fp16)
// mode 1: kv split epilogue (col<64 -> k, else v; [b*2048+i][d] fp16)
// mode 2: fp32 out + bias
__global__ __launch_bounds__(256) void gemm_kernel(
    const unsigned short* __restrict__ A, const unsigned short* __restrict__ Bt,
    int K, int mode,
    unsigned short* __restrict__ oq, unsigned short* __restrict__ ok,
    unsigned short* __restrict__ ov, float* __restrict__ of,
    const float* __restrict__ bias)
{
    __shared__ __align__(16) unsigned short As[64 * 40];
    __shared__ __align__(16) unsigned short Bs[64 * 40];
    int t = threadIdx.x;
    int w = t >> 6, lane = t & 63, g = lane >> 4, il = lane & 15;
    int m0 = blockIdx.y * 64, n0 = blockIdx.x * 64;
    int ar = t >> 2, ac = (t & 3) * 8;
    floatx4 acc[4] = {{0,0,0,0},{0,0,0,0},{0,0,0,0},{0,0,0,0}};
    const unsigned short* Ap = A + (size_t)(m0 + ar) * K + ac;
    const unsigned short* Bp = Bt + (size_t)(n0 + ar) * K + ac;
    for (int k0 = 0; k0 < K; k0 += 32) {
        ushort8 av = *(const ushort8*)(Ap + k0);
        ushort8 bv = *(const ushort8*)(Bp + k0);
        __syncthreads();
        *(ushort8*)&As[ar * 40 + ac] = av;
        *(ushort8*)&Bs[ar * 40 + ac] = bv;
        __syncthreads();
        half8 af = *(const half8*)&As[(w * 16 + il) * 40 + g * 8];
        #pragma unroll
        for (int nt = 0; nt < 4; nt++) {
            half8 bf = *(const half8*)&Bs[(nt * 16 + il) * 40 + g * 8];
            acc[nt] = __builtin_amdgcn_mfma_f32_16x16x32_f16(af, bf, acc[nt], 0, 0, 0);
        }
    }
    #pragma unroll
    for (int nt = 0; nt < 4; nt++) {
        #pragma unroll
        for (int r = 0; r < 4; r++) {
            int row = m0 + w * 16 + 4 * g + r;
            int col = n0 + nt * 16 + il;
            float v = acc[nt][r];
            if (mode == 0) {
                int b = row >> 11, i = row & 2047, h = col >> 6, d = col & 63;
                oq[(size_t)(((b * 16 + h) * 2048 + i)) * 64 + d] = f2h(v * 0.125f);
            } else if (mode == 1) {
                if (col < 64) ok[(size_t)row * 64 + col] = f2h(v);
                else          ov[(size_t)row * 64 + (col - 64)] = f2h(v);
            } else {
                of[(size_t)row * 1024 + col] = v + bias[col];
            }
        }
    }
}

// ---------------- flash attention ----------------
// Grid: (32 i-tiles, 32 b*h). Block 256 = 4 waves; wave w owns Q rows i0+16w..+15.
// Computes S^T = K.Q^T per 16x16 tile so softmax rows live per-lane (i = lane&15).
__global__ __launch_bounds__(256) void attn_kernel(
    const unsigned short* __restrict__ qh, const unsigned short* __restrict__ kh,
    const unsigned short* __restrict__ vh, const float* __restrict__ rel_emb,
    unsigned short* __restrict__ ob)
{
    __shared__ float bias_tab[2048];
    __shared__ __align__(16) unsigned short Vt[64 * 40]; // V^T tile: [d][j], stride 40
    __shared__ __align__(16) unsigned short Pl[64 * 40]; // P: per-wave 16 rows [i][j]
    int bx = blockIdx.x;
    int bh = blockIdx.y;
    int b = bh >> 4, h = bh & 15;
    int t = threadIdx.x;
    int w = t >> 6, lane = t & 63, g = lane >> 4, il = lane & 15;

    // Per-head bias table over delta = i - j in [0, 2047], matches ref fp32 math.
    for (int dlt = t; dlt < 2048; dlt += 256) {
        int bucket;
        if (dlt < 16) bucket = dlt;
        else {
            float lg = logf((float)dlt * 0.0625f) / (float)2.0794415416798357;
            int vv = 16 + (int)(lg * 16.0f);
            bucket = vv < 31 ? vv : 31;
        }
        bias_tab[dlt] = rel_emb[bucket * 16 + h] * 8.0f; // bias_scale = sqrt(64)
    }

    int i0 = bx * 64;
    int iw = i0 + w * 16;
    int i_glob = iw + il;
    const unsigned short* qrow = qh + (size_t)(bh * 2048 + iw + il) * 64;
    half8 qf0 = *(const half8*)(qrow + g * 8);
    half8 qf1 = *(const half8*)(qrow + 32 + g * 8);
    const unsigned short* kbase = kh + (size_t)b * (2048 * 64);
    const unsigned short* vbase = vh + (size_t)b * (2048 * 64);
    floatx4 O[4] = {{0,0,0,0},{0,0,0,0},{0,0,0,0},{0,0,0,0}};
    float m_run = -1e30f, l_run = 0.0f;
    int jl_st = t & 31, d0_st = (t >> 5) * 8;
    int nchunk = 2 * bx + 2;
    int prow = (w * 16 + il) * 40;

    for (int c = 0; c < nchunk; c++) {
        int j0 = c * 32;
        __syncthreads();  // protect Vt/Pl from previous iteration's readers
        // stage V^T tile (32 j x 64 d)
        ushort8 vv = *(const ushort8*)(vbase + (size_t)(j0 + jl_st) * 64 + d0_st);
        #pragma unroll
        for (int u = 0; u < 8; u++) Vt[(d0_st + u) * 40 + jl_st] = vv[u];
        __syncthreads();

        // S^T tiles: m=j (16 each), n=i, K over d=64 in two steps
        floatx4 S0 = {0,0,0,0}, S1 = {0,0,0,0};
        {
            const unsigned short* kr0 = kbase + (size_t)(j0 + il) * 64;
            half8 k00 = *(const half8*)(kr0 + g * 8);
            half8 k01 = *(const half8*)(kr0 + 32 + g * 8);
            S0 = __builtin_amdgcn_mfma_f32_16x16x32_f16(k00, qf0, S0, 0, 0, 0);
            S0 = __builtin_amdgcn_mfma_f32_16x16x32_f16(k01, qf1, S0, 0, 0, 0);
            const unsigned short* kr1 = kbase + (size_t)(j0 + 16 + il) * 64;
            half8 k10 = *(const half8*)(kr1 + g * 8);
            half8 k11 = *(const half8*)(kr1 + 32 + g * 8);
            S1 = __builtin_amdgcn_mfma_f32_16x16x32_f16(k10, qf0, S1, 0, 0, 0);
            S1 = __builtin_amdgcn_mfma_f32_16x16x32_f16(k11, qf1, S1, 0, 0, 0);
        }
        // bias + causal mask; lane holds i = i_glob, j = j0 + 16*t2 + 4g + r
        float s[8];
        #pragma unroll
        for (int t2 = 0; t2 < 2; t2++) {
            #pragma unroll
            for (int r = 0; r < 4; r++) {
                int j = j0 + t2 * 16 + 4 * g + r;
                int delta = i_glob - j;
                int di = delta > 0 ? delta : 0;
                float base = (t2 == 0 ? S0[r] : S1[r]);
                s[t2 * 4 + r] = (delta >= 0) ? (base + bias_tab[di]) : -1e30f;
            }
        }
        // online softmax, per-row = per (lane&15), reduce across 4 lane-groups
        float mx = s[0];
        #pragma unroll
        for (int q2 = 1; q2 < 8; q2++) mx = fmaxf(mx, s[q2]);
        mx = fmaxf(mx, __shfl_xor(mx, 16));
        mx = fmaxf(mx, __shfl_xor(mx, 32));
        float m_new = fmaxf(m_run, mx);
        float alpha = __expf(m_run - m_new);
        float p[8], psum = 0.0f;
        #pragma unroll
        for (int q2 = 0; q2 < 8; q2++) { p[q2] = __expf(s[q2] - m_new); psum += p[q2]; }
        psum += __shfl_xor(psum, 16);
        psum += __shfl_xor(psum, 32);
        l_run = l_run * alpha + psum;
        m_run = m_new;
        // rescale O rows (O rows are 4g+r; alpha lives at lane (lane&15)=row)
        float arow[4];
        #pragma unroll
        for (int r = 0; r < 4; r++) arow[r] = __shfl(alpha, 4 * g + r);
        #pragma unroll
        for (int dt = 0; dt < 4; dt++) {
            #pragma unroll
            for (int r = 0; r < 4; r++) O[dt][r] *= arow[r];
        }
        // write P (fp16) to per-wave LDS rows: row i=il, cols j = t2*16+4g+{0..3}
        #pragma unroll
        for (int t2 = 0; t2 < 2; t2++) {
            unsigned int u01 = (unsigned int)f2h(p[t2 * 4 + 0]) | ((unsigned int)f2h(p[t2 * 4 + 1]) << 16);
            unsigned int u23 = (unsigned int)f2h(p[t2 * 4 + 2]) | ((unsigned int)f2h(p[t2 * 4 + 3]) << 16);
            unsigned int* pp = (unsigned int*)&Pl[prow + t2 * 16 + 4 * g];
            pp[0] = u01; pp[1] = u23;
        }
        __syncthreads();  // P visible wave-wide (and uniform barrier count)
        // PV: A = P[i][j], B = V[j][d] from Vt[d][j]
        half8 pf = *(const half8*)&Pl[prow + g * 8];
        #pragma unroll
        for (int dt = 0; dt < 4; dt++) {
            half8 vf = *(const half8*)&Vt[(dt * 16 + il) * 40 + g * 8];
            O[dt] = __builtin_amdgcn_mfma_f32_16x16x32_f16(pf, vf, O[dt], 0, 0, 0);
        }
    }
    // epilogue: normalize and store to [b*2048+i][h*64+d] fp16
    float inv[4];
    #pragma unroll
    for (int r = 0; r < 4; r++) inv[r] = 1.0f / __shfl(l_run, 4 * g + r);
    #pragma unroll
    for (int dt = 0; dt < 4; dt++) {
        #pragma unroll
        for (int r = 0; r < 4; r++) {
            int i = iw + 4 * g + r;
            int d = dt * 16 + il;
            ob[(size_t)(b * 2048 + i) * 1024 + h * 64 + d] = f2h(O[dt][r] * inv[r]);
        }
    }
}

extern "C" void kernel_launch(void* const* d_in, const int* in_sizes, int n_in,
                              void* d_out, int out_size, void* d_ws, size_t ws_size,
                              hipStream_t stream) {
    const float* x    = (const float*)d_in[0];
    const float* Wq   = (const float*)d_in[1];
    const float* Wkv  = (const float*)d_in[2];
    const float* Wout = (const float*)d_in[3];
    const float* bout = (const float*)d_in[4];
    const float* rel  = (const float*)d_in[5];
    float* out = (float*)d_out;

    unsigned short* ws   = (unsigned short*)d_ws;
    unsigned short* xh   = ws;                    // 4096x1024 fp16 (x), later reused as attn_out
    unsigned short* qh   = xh + 4194304;          // [b,h,i,d] fp16, pre-scaled
    unsigned short* kh   = qh + 4194304;          // [b,i,d]
    unsigned short* vh   = kh + 262144;
    unsigned short* Wqt  = vh + 262144;           // [N=1024][K=1024]
    unsigned short* Wkvt = Wqt + 1048576;         // [128][1024]
    unsigned short* Wot  = Wkvt + 131072;         // [1024][1024]
    unsigned short* ob   = xh;                    // alias: x dead after QKV projections

    cast_x_kernel<<<2048, 256, 0, stream>>>(x, xh, 524288);
    transpose_cast_kernel<<<dim3(32, 32), dim3(32, 8), 0, stream>>>(Wq,   Wqt,  1024, 1024);
    transpose_cast_kernel<<<dim3(4, 32),  dim3(32, 8), 0, stream>>>(Wkv,  Wkvt, 1024, 128);
    transpose_cast_kernel<<<dim3(32, 32), dim3(32, 8), 0, stream>>>(Wout, Wot,  1024, 1024);
    // q projection: M=4096, N=1024
    gemm_kernel<<<dim3(16, 64), 256, 0, stream>>>(xh, Wqt, 1024, 0, qh, nullptr, nullptr, nullptr, nullptr);
    // kv projection: M=4096, N=128
    gemm_kernel<<<dim3(2, 64), 256, 0, stream>>>(xh, Wkvt, 1024, 1, nullptr, kh, vh, nullptr, nullptr);
    attn_kernel<<<dim3(32, 32), 256, 0, stream>>>(qh, kh, vh, rel, ob);
    // output projection: M=4096, N=1024, fp32 + bias
    gemm_kernel<<<dim3(16, 64), 256, 0, stream>>>(ob, Wot, 1024, 2, nullptr, nullptr, nullptr, out, bout);
}